// Round 1
// baseline (4218.922 us; speedup 1.0000x reference)
//
#include <hip/hip_runtime.h>

#define B_ 128
#define T_ 100
#define D_ 256
#define H_ 512
#define L_ 40000
#define S_ 10

__device__ __forceinline__ float sigm_(float x){ return 1.f/(1.f + __expf(-x)); }
__device__ __forceinline__ float tanh_(float x){ return 1.f - 2.f/(__expf(2.f*x) + 1.f); }

// ---------------- zero h double-buffer + sync counters ----------------
__global__ void k_zero(float* __restrict__ h_buf, unsigned* __restrict__ cnt){
  int idx = blockIdx.x*256 + threadIdx.x;   // grid 512 -> exactly 2*B*H
  h_buf[idx] = 0.f;
  if (blockIdx.x == 0 && threadIdx.x < 16) cnt[threadIdx.x] = 0u;
}

// ---------------- slot projections: Es/Eq = embed @ W_o.T (10 x 512) ----------------
__global__ void k_prep(const float* __restrict__ embed_s, const float* __restrict__ embed_q,
                       const float* __restrict__ w_s, const float* __restrict__ w_q,
                       float* __restrict__ es_proj, float* __restrict__ eq_proj){
  int bid = blockIdx.x;                 // 40 blocks
  int table = bid/20, rem = bid%20, s = rem/2, half = rem%2;
  int jo = half*256 + threadIdx.x;
  const float* emb = (table ? embed_q : embed_s) + s*D_;
  const float* w   = (table ? w_q : w_s) + (size_t)(2*H_ + jo)*D_;   // o-gate rows
  float acc = 0.f;
  #pragma unroll 4
  for (int k=0;k<D_;++k) acc = fmaf(emb[k], w[k], acc);
  (table ? eq_proj : es_proj)[s*H_ + jo] = acc;
}

// ---------------- phase 1: P[t][b][j], j<512 = g-gate preact, j>=512 = o-gate preact ----------------
__global__ __launch_bounds__(256) void k_phase1(
  const int* __restrict__ batch_l, const float* __restrict__ embed_l,
  const float* __restrict__ w_ih, const float* __restrict__ b_ih, const float* __restrict__ b_hh,
  const float* __restrict__ t_ld, const float* __restrict__ t_hd,
  const int* __restrict__ t_l, const int* __restrict__ t_h,
  const float* __restrict__ d_ld, const float* __restrict__ d_hd,
  const int* __restrict__ d_l, const int* __restrict__ d_h,
  const float* __restrict__ es_proj, const float* __restrict__ eq_proj,
  float* __restrict__ P)
{
  __shared__ float As[8][72];
  __shared__ float Bs[8][72];
  __shared__ int ridx[64];
  int mt = blockIdx.x, jt = blockIdx.y;       // 200 x 16
  int t = mt >> 1, b0 = (mt & 1)*64;          // one t, 64 consecutive b per m-tile
  int tid = threadIdx.x;
  if (tid < 64) ridx[tid] = batch_l[(b0+tid)*T_ + t];
  __syncthreads();
  int ty = tid >> 4, tx = tid & 15;
  int r_s = tid >> 2;                         // staging: element e = tid*2
  int kk_s = (tid & 3)*2;
  const float* arow = embed_l + (size_t)ridx[r_s]*D_ + kk_s;
  const float* brow = w_ih + (size_t)(2*H_ + jt*64 + r_s)*D_ + kk_s;
  float acc[4][4] = {};
  for (int kc = 0; kc < 32; ++kc) {
    int k0 = kc*8;
    float2 av = *(const float2*)(arow + k0);
    float2 bv = *(const float2*)(brow + k0);
    __syncthreads();
    As[kk_s][r_s] = av.x; As[kk_s+1][r_s] = av.y;
    Bs[kk_s][r_s] = bv.x; Bs[kk_s+1][r_s] = bv.y;
    __syncthreads();
    #pragma unroll
    for (int kk=0;kk<8;++kk){
      float4 a4 = *(const float4*)&As[kk][ty*4];
      float4 b4 = *(const float4*)&Bs[kk][tx*4];
      float avv[4] = {a4.x,a4.y,a4.z,a4.w};
      float bvv[4] = {b4.x,b4.y,b4.z,b4.w};
      #pragma unroll
      for (int i=0;i<4;++i)
        #pragma unroll
        for (int j=0;j<4;++j) acc[i][j] = fmaf(avv[i], bvv[j], acc[i][j]);
    }
  }
  int j0 = jt*64 + tx*4;
  float bias[4];
  #pragma unroll
  for (int j=0;j<4;++j) bias[j] = b_ih[2*H_ + j0 + j] + b_hh[2*H_ + j0 + j];
  #pragma unroll
  for (int i=0;i<4;++i){
    int b = b0 + ty*4 + i;
    size_t m = (size_t)t*B_ + b;
    float add[4] = {0.f,0.f,0.f,0.f};
    if (jt >= 8) {      // o-gate columns: add slot/query interpolation
      int bt = b*T_ + t;
      float dld = d_ld[bt], dhd = d_hd[bt];
      float tld = t_ld[bt], thd = t_hd[bt];
      int dl = d_l[bt], dh = d_h[bt], tl = t_l[bt], th = t_h[bt];
      int jo = j0 - 512;
      #pragma unroll
      for (int j=0;j<4;++j)
        add[j] = dhd*es_proj[dl*H_+jo+j] + dld*es_proj[dh*H_+jo+j]
               + thd*eq_proj[tl*H_+jo+j] + tld*eq_proj[th*H_+jo+j];
    }
    float4 o4;
    o4.x = acc[i][0] + bias[0] + add[0];
    o4.y = acc[i][1] + bias[1] + add[1];
    o4.z = acc[i][2] + bias[2] + add[2];
    o4.w = acc[i][3] + bias[3] + add[3];
    *(float4*)&P[m*1024 + j0] = o4;
  }
}

// ---------------- recurrence: persistent, 256 WGs = 16 batch-groups x 16 j-slices ----------------
// WG holds its 64 Whh rows (g+o for 32 jh) in LDS k-major; h exchanged via global double buffer,
// per-batch-group 16-WG sync via device-scope release/acquire counter.
__global__ __launch_bounds__(256,1) void k_rec(
  const float* __restrict__ w_hh, const float* __restrict__ P,
  float* __restrict__ h_buf, unsigned* __restrict__ cnt)
{
  extern __shared__ float sm[];
  float* Wt = sm;                 // [512][66] k-major: Wt[k*66 + r], r = 4*rq + {g0,g1,o0,o1}
  float* ht = sm + 512*66;        // [512][13] k-major: ht[k*13 + b]
  int bid = blockIdx.x;
  int bg = bid & 15, js = bid >> 4;
  int tid = threadIdx.x;
  const float* Wgo = w_hh + (size_t)2*H_*H_;      // rows [0,512)=g, [512,1024)=o
  for (int it=0; it<32; ++it){                    // stage 64x512 weights
    int e4 = (it*256 + tid)*4;
    int k = e4 & 511, r = e4 >> 9;
    int jh_loc = 2*(r>>2) + (r&1);
    int part = (r>>1)&1;
    int grow = part*H_ + js*32 + jh_loc;
    float4 v = *(const float4*)(Wgo + (size_t)grow*H_ + k);
    Wt[(k+0)*66 + r] = v.x; Wt[(k+1)*66 + r] = v.y;
    Wt[(k+2)*66 + r] = v.z; Wt[(k+3)*66 + r] = v.w;
  }
  int rq = tid >> 4, kq = tid & 15;
  unsigned target = 0;
  for (int t=0; t<T_; ++t){
    int par = t & 1;
    const float* hb = h_buf + par*(B_*H_) + (bg*8)*H_;
    __syncthreads();
    #pragma unroll
    for (int b=0;b<8;++b){                         // stage h[8][512] -> k-major LDS
      ht[tid*13 + b]       = hb[b*H_ + tid];
      ht[(256+tid)*13 + b] = hb[b*H_ + 256 + tid];
    }
    __syncthreads();
    float acc[4][8] = {};
    #pragma unroll 4
    for (int kk=0; kk<32; ++kk){
      int k = kk*16 + kq;                          // kq-interleaved k to spread LDS banks
      float2 wA = *(const float2*)&Wt[k*66 + 4*rq];
      float2 wB = *(const float2*)&Wt[k*66 + 4*rq + 2];
      float w0=wA.x, w1=wA.y, w2=wB.x, w3=wB.y;
      float hv[8];
      #pragma unroll
      for (int b=0;b<8;++b) hv[b] = ht[k*13 + b];
      #pragma unroll
      for (int b=0;b<8;++b){
        acc[0][b] = fmaf(w0, hv[b], acc[0][b]);
        acc[1][b] = fmaf(w1, hv[b], acc[1][b]);
        acc[2][b] = fmaf(w2, hv[b], acc[2][b]);
        acc[3][b] = fmaf(w3, hv[b], acc[3][b]);
      }
    }
    #pragma unroll
    for (int m=0;m<4;++m)
      #pragma unroll
      for (int b=0;b<8;++b){
        float v = acc[m][b];
        v += __shfl_xor(v, 1, 64);
        v += __shfl_xor(v, 2, 64);
        v += __shfl_xor(v, 4, 64);
        v += __shfl_xor(v, 8, 64);
        acc[m][b] = v;
      }
    if (kq < 8){
      int b = kq;
      int gb = bg*8 + b;
      size_t prow = ((size_t)t*B_ + gb)*1024;
      int jcol = js*32 + 2*rq;
      float2 pg = *(const float2*)&P[prow + jcol];
      float2 po = *(const float2*)&P[prow + 512 + jcol];
      float gg0 = acc[0][b] + pg.x, gg1 = acc[1][b] + pg.y;
      float oo0 = acc[2][b] + po.x, oo1 = acc[3][b] + po.y;
      float2 h2;
      h2.x = sigm_(oo0)*tanh_(tanh_(gg0));
      h2.y = sigm_(oo1)*tanh_(tanh_(gg1));
      *(float2*)&h_buf[(1-par)*(B_*H_) + gb*H_ + jcol] = h2;
    }
    __syncthreads();   // drains each wave's stores (vmcnt 0) before barrier
    if (tid == 0)
      __hip_atomic_fetch_add(&cnt[bg], 1u, __ATOMIC_RELEASE, __HIP_MEMORY_SCOPE_AGENT);
    target += 16;
    int guard = 0;
    while (__hip_atomic_load(&cnt[bg], __ATOMIC_ACQUIRE, __HIP_MEMORY_SCOPE_AGENT) < target){
      if (++guard > (1<<21)) break;                // safety bail (never in normal operation)
      __builtin_amdgcn_s_sleep(2);
    }
  }
}

// ---------------- classifier: out = hT @ w_out.T + b_out ----------------
__global__ __launch_bounds__(256) void k_cls(
  const float* __restrict__ hT, const float* __restrict__ w_out,
  const float* __restrict__ b_out, float* __restrict__ out)
{
  __shared__ float wt[32*68];     // [k][l] k-major
  __shared__ float htl[32*132];   // [k][b]
  int l0 = blockIdx.x * 64;       // 625 blocks
  int tid = threadIdx.x;
  int lq = tid >> 4, bq = tid & 15;
  float acc[4][8] = {};
  for (int kc=0; kc<16; ++kc){
    int k0 = kc*32;
    __syncthreads();
    for (int it=0; it<8; ++it){
      int e = it*256 + tid; int k = e & 31, l = e >> 5;
      wt[k*68 + l] = w_out[(size_t)(l0+l)*H_ + k0 + k];
    }
    for (int it=0; it<16; ++it){
      int e = it*256 + tid; int k = e & 31, b = e >> 5;
      htl[k*132 + b] = hT[b*H_ + k0 + k];
    }
    __syncthreads();
    #pragma unroll 4
    for (int k=0;k<32;++k){
      float4 w4 = *(const float4*)&wt[k*68 + lq*4];
      float4 h0 = *(const float4*)&htl[k*132 + bq*8];
      float4 h1 = *(const float4*)&htl[k*132 + bq*8 + 4];
      float wv[4] = {w4.x,w4.y,w4.z,w4.w};
      float hv[8] = {h0.x,h0.y,h0.z,h0.w,h1.x,h1.y,h1.z,h1.w};
      #pragma unroll
      for (int m=0;m<4;++m)
        #pragma unroll
        for (int i=0;i<8;++i) acc[m][i] = fmaf(wv[m], hv[i], acc[m][i]);
    }
  }
  int l = l0 + lq*4;
  float4 bo = *(const float4*)&b_out[l];
  #pragma unroll
  for (int i=0;i<8;++i){
    int b = bq*8 + i;
    float4 o4;
    o4.x = acc[0][i] + bo.x; o4.y = acc[1][i] + bo.y;
    o4.z = acc[2][i] + bo.z; o4.w = acc[3][i] + bo.w;
    *(float4*)&out[(size_t)b*L_ + l] = o4;
  }
}

extern "C" void kernel_launch(void* const* d_in, const int* in_sizes, int n_in,
                              void* d_out, int out_size, void* d_ws, size_t ws_size,
                              hipStream_t stream) {
  const int*   batch_l = (const int*)  d_in[0];
  const float* t_ld    = (const float*)d_in[1];
  const float* t_hd    = (const float*)d_in[2];
  const int*   t_l     = (const int*)  d_in[3];
  const int*   t_h     = (const int*)  d_in[4];
  const float* d_ld    = (const float*)d_in[5];
  const float* d_hd    = (const float*)d_in[6];
  const int*   d_l     = (const int*)  d_in[7];
  const int*   d_h     = (const int*)  d_in[8];
  const float* embed_l = (const float*)d_in[9];
  const float* embed_s = (const float*)d_in[10];
  const float* embed_q = (const float*)d_in[11];
  const float* w_ih    = (const float*)d_in[12];
  const float* w_hh    = (const float*)d_in[13];
  const float* w_s     = (const float*)d_in[14];
  const float* w_q     = (const float*)d_in[15];
  const float* b_ih    = (const float*)d_in[16];
  const float* b_hh    = (const float*)d_in[17];
  const float* w_out   = (const float*)d_in[18];
  const float* b_out   = (const float*)d_in[19];
  float* out = (float*)d_out;

  // workspace layout (floats)
  float* ws = (float*)d_ws;
  const size_t P_off  = 0;                          // 100*128*1024 = 13107200
  const size_t h_off  = 13107200;                   // 2*128*512 = 131072
  const size_t es_off = h_off + 131072;             // 5120
  const size_t eq_off = es_off + 5120;              // 5120
  const size_t cnt_off = eq_off + 5120;             // 16 u32
  const size_t need_bytes = (cnt_off)*4 + 64;
  if (ws_size < need_bytes) return;                 // fail visibly rather than corrupt

  float* P       = ws + P_off;
  float* h_buf   = ws + h_off;
  float* es_proj = ws + es_off;
  float* eq_proj = ws + eq_off;
  unsigned* cnt  = (unsigned*)(ws + cnt_off);

  hipFuncSetAttribute(reinterpret_cast<const void*>(k_rec),
                      hipFuncAttributeMaxDynamicSharedMemorySize, 161792);

  k_zero<<<512, 256, 0, stream>>>(h_buf, cnt);
  k_prep<<<40, 256, 0, stream>>>(embed_s, embed_q, w_s, w_q, es_proj, eq_proj);
  k_phase1<<<dim3(200,16), 256, 0, stream>>>(batch_l, embed_l, w_ih, b_ih, b_hh,
      t_ld, t_hd, t_l, t_h, d_ld, d_hd, d_l, d_h, es_proj, eq_proj, P);
  k_rec<<<256, 256, 161792, stream>>>(w_hh, P, h_buf, cnt);
  k_cls<<<625, 256, 0, stream>>>(h_buf, w_out, b_out, out);
}

// Round 2
// 1479.777 us; speedup vs baseline: 2.8511x; 2.8511x over previous
//
#include <hip/hip_runtime.h>

#define B_ 128
#define T_ 100
#define D_ 256
#define H_ 512
#define L_ 40000
#define S_ 10

__device__ __forceinline__ float sigm_(float x){ return 1.f/(1.f + __expf(-x)); }
__device__ __forceinline__ float tanh_(float x){ return 1.f - 2.f/(__expf(2.f*x) + 1.f); }

// ---------------- zero h double-buffer + padded sync counters ----------------
__global__ void k_zero(float* __restrict__ h_buf, unsigned* __restrict__ cnt){
  int idx = blockIdx.x*256 + threadIdx.x;
  if (blockIdx.x < 512) h_buf[idx] = 0.f;            // 512*256 = 2*B*H
  else cnt[idx - 512*256] = 0u;                      // blocks 512..515 -> 1024 u32
}

// ---------------- slot projections: Es/Eq = embed @ W_o.T (10 x 512) ----------------
__global__ void k_prep(const float* __restrict__ embed_s, const float* __restrict__ embed_q,
                       const float* __restrict__ w_s, const float* __restrict__ w_q,
                       float* __restrict__ es_proj, float* __restrict__ eq_proj){
  int bid = blockIdx.x;                 // 40 blocks
  int table = bid/20, rem = bid%20, s = rem/2, half = rem%2;
  int jo = half*256 + threadIdx.x;
  const float* emb = (table ? embed_q : embed_s) + s*D_;
  const float* w   = (table ? w_q : w_s) + (size_t)(2*H_ + jo)*D_;   // o-gate rows
  float acc = 0.f;
  #pragma unroll 4
  for (int k=0;k<D_;++k) acc = fmaf(emb[k], w[k], acc);
  (table ? eq_proj : es_proj)[s*H_ + jo] = acc;
}

// ---------------- phase 1: P[t][b][j], j<512 = g-gate preact, j>=512 = o-gate preact ----------------
__global__ __launch_bounds__(256) void k_phase1(
  const int* __restrict__ batch_l, const float* __restrict__ embed_l,
  const float* __restrict__ w_ih, const float* __restrict__ b_ih, const float* __restrict__ b_hh,
  const float* __restrict__ t_ld, const float* __restrict__ t_hd,
  const int* __restrict__ t_l, const int* __restrict__ t_h,
  const float* __restrict__ d_ld, const float* __restrict__ d_hd,
  const int* __restrict__ d_l, const int* __restrict__ d_h,
  const float* __restrict__ es_proj, const float* __restrict__ eq_proj,
  float* __restrict__ P)
{
  __shared__ float As[8][72];
  __shared__ float Bs[8][72];
  __shared__ int ridx[64];
  int mt = blockIdx.x, jt = blockIdx.y;       // 200 x 16
  int t = mt >> 1, b0 = (mt & 1)*64;
  int tid = threadIdx.x;
  if (tid < 64) ridx[tid] = batch_l[(b0+tid)*T_ + t];
  __syncthreads();
  int ty = tid >> 4, tx = tid & 15;
  int r_s = tid >> 2;
  int kk_s = (tid & 3)*2;
  const float* arow = embed_l + (size_t)ridx[r_s]*D_ + kk_s;
  const float* brow = w_ih + (size_t)(2*H_ + jt*64 + r_s)*D_ + kk_s;
  float acc[4][4] = {};
  for (int kc = 0; kc < 32; ++kc) {
    int k0 = kc*8;
    float2 av = *(const float2*)(arow + k0);
    float2 bv = *(const float2*)(brow + k0);
    __syncthreads();
    As[kk_s][r_s] = av.x; As[kk_s+1][r_s] = av.y;
    Bs[kk_s][r_s] = bv.x; Bs[kk_s+1][r_s] = bv.y;
    __syncthreads();
    #pragma unroll
    for (int kk=0;kk<8;++kk){
      float4 a4 = *(const float4*)&As[kk][ty*4];
      float4 b4 = *(const float4*)&Bs[kk][tx*4];
      float avv[4] = {a4.x,a4.y,a4.z,a4.w};
      float bvv[4] = {b4.x,b4.y,b4.z,b4.w};
      #pragma unroll
      for (int i=0;i<4;++i)
        #pragma unroll
        for (int j=0;j<4;++j) acc[i][j] = fmaf(avv[i], bvv[j], acc[i][j]);
    }
  }
  int j0 = jt*64 + tx*4;
  float bias[4];
  #pragma unroll
  for (int j=0;j<4;++j) bias[j] = b_ih[2*H_ + j0 + j] + b_hh[2*H_ + j0 + j];
  #pragma unroll
  for (int i=0;i<4;++i){
    int b = b0 + ty*4 + i;
    size_t m = (size_t)t*B_ + b;
    float add[4] = {0.f,0.f,0.f,0.f};
    if (jt >= 8) {
      int bt = b*T_ + t;
      float dld = d_ld[bt], dhd = d_hd[bt];
      float tld = t_ld[bt], thd = t_hd[bt];
      int dl = d_l[bt], dh = d_h[bt], tl = t_l[bt], th = t_h[bt];
      int jo = j0 - 512;
      #pragma unroll
      for (int j=0;j<4;++j)
        add[j] = dhd*es_proj[dl*H_+jo+j] + dld*es_proj[dh*H_+jo+j]
               + thd*eq_proj[tl*H_+jo+j] + tld*eq_proj[th*H_+jo+j];
    }
    float4 o4;
    o4.x = acc[i][0] + bias[0] + add[0];
    o4.y = acc[i][1] + bias[1] + add[1];
    o4.z = acc[i][2] + bias[2] + add[2];
    o4.w = acc[i][3] + bias[3] + add[3];
    *(float4*)&P[m*1024 + j0] = o4;
  }
}

// ---------------- recurrence: persistent, 256 WGs = 16 batch-groups x 16 j-slices ----------------
// Sync fix vs round 0: counters padded to 256B, single-thread relaxed spin + one acquire,
// P prefetch for t+1 issued before the poll so it hides under the wait.
__global__ __launch_bounds__(256,1) void k_rec(
  const float* __restrict__ w_hh, const float* __restrict__ P,
  float* __restrict__ h_buf, unsigned* __restrict__ cnt)
{
  extern __shared__ float sm[];
  float* Wt = sm;                 // [512][66] k-major: Wt[k*66 + r]
  float* ht = sm + 512*66;        // [512][13] k-major: ht[k*13 + b]
  int bid = blockIdx.x;
  int bg = bid & 15, js = bid >> 4;
  int tid = threadIdx.x;
  const float* Wgo = w_hh + (size_t)2*H_*H_;      // rows [0,512)=g, [512,1024)=o
  for (int it=0; it<32; ++it){                    // stage 64x512 weights
    int e4 = (it*256 + tid)*4;
    int k = e4 & 511, r = e4 >> 9;
    int jh_loc = 2*(r>>2) + (r&1);
    int part = (r>>1)&1;
    int grow = part*H_ + js*32 + jh_loc;
    float4 v = *(const float4*)(Wgo + (size_t)grow*H_ + k);
    Wt[(k+0)*66 + r] = v.x; Wt[(k+1)*66 + r] = v.y;
    Wt[(k+2)*66 + r] = v.z; Wt[(k+3)*66 + r] = v.w;
  }
  int rq = tid >> 4, kq = tid & 15;
  unsigned* mycnt = cnt + bg*64;                  // 256B-padded counter
  int gb = bg*8 + kq;                             // valid when kq<8
  int jcol = js*32 + 2*rq;
  float2 pg = {0.f,0.f}, po = {0.f,0.f};
  if (kq < 8){
    size_t prow = (size_t)gb*1024;                // t = 0
    pg = *(const float2*)&P[prow + jcol];
    po = *(const float2*)&P[prow + 512 + jcol];
  }
  unsigned target = 0;
  for (int t=0; t<T_; ++t){
    int par = t & 1;
    const float* hb = h_buf + par*(B_*H_) + (bg*8)*H_;
    __syncthreads();
    #pragma unroll
    for (int b=0;b<8;++b){                         // stage h[8][512] -> k-major LDS
      ht[tid*13 + b]       = hb[b*H_ + tid];
      ht[(256+tid)*13 + b] = hb[b*H_ + 256 + tid];
    }
    __syncthreads();
    float acc[4][8] = {};
    #pragma unroll 4
    for (int kk=0; kk<32; ++kk){
      int k = kk*16 + kq;
      float2 wA = *(const float2*)&Wt[k*66 + 4*rq];
      float2 wB = *(const float2*)&Wt[k*66 + 4*rq + 2];
      float w0=wA.x, w1=wA.y, w2=wB.x, w3=wB.y;
      float hv[8];
      #pragma unroll
      for (int b=0;b<8;++b) hv[b] = ht[k*13 + b];
      #pragma unroll
      for (int b=0;b<8;++b){
        acc[0][b] = fmaf(w0, hv[b], acc[0][b]);
        acc[1][b] = fmaf(w1, hv[b], acc[1][b]);
        acc[2][b] = fmaf(w2, hv[b], acc[2][b]);
        acc[3][b] = fmaf(w3, hv[b], acc[3][b]);
      }
    }
    #pragma unroll
    for (int m=0;m<4;++m)
      #pragma unroll
      for (int b=0;b<8;++b){
        float v = acc[m][b];
        v += __shfl_xor(v, 1, 64);
        v += __shfl_xor(v, 2, 64);
        v += __shfl_xor(v, 4, 64);
        v += __shfl_xor(v, 8, 64);
        acc[m][b] = v;
      }
    if (kq < 8){
      int b = kq;
      float gg0 = acc[0][b] + pg.x, gg1 = acc[1][b] + pg.y;
      float oo0 = acc[2][b] + po.x, oo1 = acc[3][b] + po.y;
      float2 h2;
      h2.x = sigm_(oo0)*tanh_(tanh_(gg0));
      h2.y = sigm_(oo1)*tanh_(tanh_(gg1));
      *(float2*)&h_buf[(1-par)*(B_*H_) + gb*H_ + jcol] = h2;
    }
    __syncthreads();   // waves drain stores (vmcnt 0) before barrier
    if (tid == 0)
      __hip_atomic_fetch_add(mycnt, 1u, __ATOMIC_RELEASE, __HIP_MEMORY_SCOPE_AGENT);
    // prefetch next step's P while we wait
    if (t+1 < T_ && kq < 8){
      size_t prow = ((size_t)(t+1)*B_ + gb)*1024;
      pg = *(const float2*)&P[prow + jcol];
      po = *(const float2*)&P[prow + 512 + jcol];
    }
    target += 16;
    if (tid == 0){
      int guard = 0;
      while (__hip_atomic_load(mycnt, __ATOMIC_RELAXED, __HIP_MEMORY_SCOPE_AGENT) < target){
        __builtin_amdgcn_s_sleep(1);
        if (++guard > (1<<20)) break;              // safety bail
      }
      (void)__hip_atomic_load(mycnt, __ATOMIC_ACQUIRE, __HIP_MEMORY_SCOPE_AGENT);
    }
    __syncthreads();
  }
}

// ---------------- classifier: out = hT @ w_out.T + b_out ----------------
__global__ __launch_bounds__(256) void k_cls(
  const float* __restrict__ hT, const float* __restrict__ w_out,
  const float* __restrict__ b_out, float* __restrict__ out)
{
  __shared__ float wt[32*68];     // [k][l] k-major
  __shared__ float htl[32*132];   // [k][b]
  int l0 = blockIdx.x * 64;       // 625 blocks
  int tid = threadIdx.x;
  int lq = tid >> 4, bq = tid & 15;
  float acc[4][8] = {};
  for (int kc=0; kc<16; ++kc){
    int k0 = kc*32;
    __syncthreads();
    for (int it=0; it<8; ++it){
      int e = it*256 + tid; int k = e & 31, l = e >> 5;
      wt[k*68 + l] = w_out[(size_t)(l0+l)*H_ + k0 + k];
    }
    for (int it=0; it<16; ++it){
      int e = it*256 + tid; int k = e & 31, b = e >> 5;
      htl[k*132 + b] = hT[b*H_ + k0 + k];
    }
    __syncthreads();
    #pragma unroll 4
    for (int k=0;k<32;++k){
      float4 w4 = *(const float4*)&wt[k*68 + lq*4];
      float4 h0 = *(const float4*)&htl[k*132 + bq*8];
      float4 h1 = *(const float4*)&htl[k*132 + bq*8 + 4];
      float wv[4] = {w4.x,w4.y,w4.z,w4.w};
      float hv[8] = {h0.x,h0.y,h0.z,h0.w,h1.x,h1.y,h1.z,h1.w};
      #pragma unroll
      for (int m=0;m<4;++m)
        #pragma unroll
        for (int i=0;i<8;++i) acc[m][i] = fmaf(wv[m], hv[i], acc[m][i]);
    }
  }
  int l = l0 + lq*4;
  float4 bo = *(const float4*)&b_out[l];
  #pragma unroll
  for (int i=0;i<8;++i){
    int b = bq*8 + i;
    float4 o4;
    o4.x = acc[0][i] + bo.x; o4.y = acc[1][i] + bo.y;
    o4.z = acc[2][i] + bo.z; o4.w = acc[3][i] + bo.w;
    *(float4*)&out[(size_t)b*L_ + l] = o4;
  }
}

extern "C" void kernel_launch(void* const* d_in, const int* in_sizes, int n_in,
                              void* d_out, int out_size, void* d_ws, size_t ws_size,
                              hipStream_t stream) {
  const int*   batch_l = (const int*)  d_in[0];
  const float* t_ld    = (const float*)d_in[1];
  const float* t_hd    = (const float*)d_in[2];
  const int*   t_l     = (const int*)  d_in[3];
  const int*   t_h     = (const int*)  d_in[4];
  const float* d_ld    = (const float*)d_in[5];
  const float* d_hd    = (const float*)d_in[6];
  const int*   d_l     = (const int*)  d_in[7];
  const int*   d_h     = (const int*)  d_in[8];
  const float* embed_l = (const float*)d_in[9];
  const float* embed_s = (const float*)d_in[10];
  const float* embed_q = (const float*)d_in[11];
  const float* w_ih    = (const float*)d_in[12];
  const float* w_hh    = (const float*)d_in[13];
  const float* w_s     = (const float*)d_in[14];
  const float* w_q     = (const float*)d_in[15];
  const float* b_ih    = (const float*)d_in[16];
  const float* b_hh    = (const float*)d_in[17];
  const float* w_out   = (const float*)d_in[18];
  const float* b_out   = (const float*)d_in[19];
  float* out = (float*)d_out;

  // workspace layout (floats)
  float* ws = (float*)d_ws;
  const size_t P_off  = 0;                          // 100*128*1024 = 13107200
  const size_t h_off  = 13107200;                   // 2*128*512 = 131072
  const size_t es_off = h_off + 131072;             // 5120
  const size_t eq_off = es_off + 5120;              // 5120
  const size_t cnt_off = eq_off + 5120;             // 1024 u32 (16 counters, 256B apart)
  const size_t need_bytes = (cnt_off + 1024)*4 + 64;
  if (ws_size < need_bytes) return;

  float* P       = ws + P_off;
  float* h_buf   = ws + h_off;
  float* es_proj = ws + es_off;
  float* eq_proj = ws + eq_off;
  unsigned* cnt  = (unsigned*)(ws + cnt_off);

  hipFuncSetAttribute(reinterpret_cast<const void*>(k_rec),
                      hipFuncAttributeMaxDynamicSharedMemorySize, 161792);

  k_zero<<<516, 256, 0, stream>>>(h_buf, cnt);
  k_prep<<<40, 256, 0, stream>>>(embed_s, embed_q, w_s, w_q, es_proj, eq_proj);
  k_phase1<<<dim3(200,16), 256, 0, stream>>>(batch_l, embed_l, w_ih, b_ih, b_hh,
      t_ld, t_hd, t_l, t_h, d_ld, d_hd, d_l, d_h, es_proj, eq_proj, P);
  k_rec<<<256, 256, 161792, stream>>>(w_hh, P, h_buf, cnt);
  k_cls<<<625, 256, 0, stream>>>(h_buf, w_out, b_out, out);
}

// Round 3
// 1034.863 us; speedup vs baseline: 4.0768x; 1.4299x over previous
//
#include <hip/hip_runtime.h>

#define B_ 128
#define T_ 100
#define D_ 256
#define H_ 512
#define L_ 40000
#define S_ 10

__device__ __forceinline__ float sigm_(float x){ return 1.f/(1.f + __expf(-x)); }
__device__ __forceinline__ float tanh_(float x){ return 1.f - 2.f/(__expf(2.f*x) + 1.f); }

union F2U64 { float2 f; unsigned long long u; };

// ---------------- zero h double-buffer + padded sync counters ----------------
__global__ void k_zero(float* __restrict__ h_buf, unsigned* __restrict__ cnt){
  int idx = blockIdx.x*256 + threadIdx.x;
  if (blockIdx.x < 512) h_buf[idx] = 0.f;            // 512*256 = 2*B*H
  else cnt[idx - 512*256] = 0u;                      // blocks 512..515 -> 1024 u32
}

// ---------------- slot projections: Es/Eq = embed @ W_o.T (10 x 512) ----------------
__global__ void k_prep(const float* __restrict__ embed_s, const float* __restrict__ embed_q,
                       const float* __restrict__ w_s, const float* __restrict__ w_q,
                       float* __restrict__ es_proj, float* __restrict__ eq_proj){
  int bid = blockIdx.x;                 // 40 blocks
  int table = bid/20, rem = bid%20, s = rem/2, half = rem%2;
  int jo = half*256 + threadIdx.x;
  const float* emb = (table ? embed_q : embed_s) + s*D_;
  const float* w   = (table ? w_q : w_s) + (size_t)(2*H_ + jo)*D_;   // o-gate rows
  float acc = 0.f;
  #pragma unroll 4
  for (int k=0;k<D_;++k) acc = fmaf(emb[k], w[k], acc);
  (table ? eq_proj : es_proj)[s*H_ + jo] = acc;
}

// ---------------- phase 1: P[t][b][j], j<512 = g-gate preact, j>=512 = o-gate preact ----------------
__global__ __launch_bounds__(256) void k_phase1(
  const int* __restrict__ batch_l, const float* __restrict__ embed_l,
  const float* __restrict__ w_ih, const float* __restrict__ b_ih, const float* __restrict__ b_hh,
  const float* __restrict__ t_ld, const float* __restrict__ t_hd,
  const int* __restrict__ t_l, const int* __restrict__ t_h,
  const float* __restrict__ d_ld, const float* __restrict__ d_hd,
  const int* __restrict__ d_l, const int* __restrict__ d_h,
  const float* __restrict__ es_proj, const float* __restrict__ eq_proj,
  float* __restrict__ P)
{
  __shared__ float As[8][72];
  __shared__ float Bs[8][72];
  __shared__ int ridx[64];
  int mt = blockIdx.x, jt = blockIdx.y;       // 200 x 16
  int t = mt >> 1, b0 = (mt & 1)*64;
  int tid = threadIdx.x;
  if (tid < 64) ridx[tid] = batch_l[(b0+tid)*T_ + t];
  __syncthreads();
  int ty = tid >> 4, tx = tid & 15;
  int r_s = tid >> 2;
  int kk_s = (tid & 3)*2;
  const float* arow = embed_l + (size_t)ridx[r_s]*D_ + kk_s;
  const float* brow = w_ih + (size_t)(2*H_ + jt*64 + r_s)*D_ + kk_s;
  float acc[4][4] = {};
  for (int kc = 0; kc < 32; ++kc) {
    int k0 = kc*8;
    float2 av = *(const float2*)(arow + k0);
    float2 bv = *(const float2*)(brow + k0);
    __syncthreads();
    As[kk_s][r_s] = av.x; As[kk_s+1][r_s] = av.y;
    Bs[kk_s][r_s] = bv.x; Bs[kk_s+1][r_s] = bv.y;
    __syncthreads();
    #pragma unroll
    for (int kk=0;kk<8;++kk){
      float4 a4 = *(const float4*)&As[kk][ty*4];
      float4 b4 = *(const float4*)&Bs[kk][tx*4];
      float avv[4] = {a4.x,a4.y,a4.z,a4.w};
      float bvv[4] = {b4.x,b4.y,b4.z,b4.w};
      #pragma unroll
      for (int i=0;i<4;++i)
        #pragma unroll
        for (int j=0;j<4;++j) acc[i][j] = fmaf(avv[i], bvv[j], acc[i][j]);
    }
  }
  int j0 = jt*64 + tx*4;
  float bias[4];
  #pragma unroll
  for (int j=0;j<4;++j) bias[j] = b_ih[2*H_ + j0 + j] + b_hh[2*H_ + j0 + j];
  #pragma unroll
  for (int i=0;i<4;++i){
    int b = b0 + ty*4 + i;
    size_t m = (size_t)t*B_ + b;
    float add[4] = {0.f,0.f,0.f,0.f};
    if (jt >= 8) {
      int bt = b*T_ + t;
      float dld = d_ld[bt], dhd = d_hd[bt];
      float tld = t_ld[bt], thd = t_hd[bt];
      int dl = d_l[bt], dh = d_h[bt], tl = t_l[bt], th = t_h[bt];
      int jo = j0 - 512;
      #pragma unroll
      for (int j=0;j<4;++j)
        add[j] = dhd*es_proj[dl*H_+jo+j] + dld*es_proj[dh*H_+jo+j]
               + thd*eq_proj[tl*H_+jo+j] + tld*eq_proj[th*H_+jo+j];
    }
    float4 o4;
    o4.x = acc[i][0] + bias[0] + add[0];
    o4.y = acc[i][1] + bias[1] + add[1];
    o4.z = acc[i][2] + bias[2] + add[2];
    o4.w = acc[i][3] + bias[3] + add[3];
    *(float4*)&P[m*1024 + j0] = o4;
  }
}

// ---------------- recurrence: persistent, 256 WGs = 16 batch-groups x 16 j-slices ----------------
// Round-2 fix: NO release/acquire fences (they emitted buffer_wbl2/buffer_inv = full per-XCD
// L2 walks, 256x per step). All cross-WG traffic (h, counters) uses RELAXED agent-scope
// atomics, which are serviced at the LLC and bypass L1/L2 — no cache maintenance at all.
// Ordering: h atomic-stores -> __syncthreads (vmcnt(0): stores ACKed at LLC) -> relaxed
// counter add; poller sees counter => h already visible to its post-barrier atomic loads.
__global__ __launch_bounds__(256,1) void k_rec(
  const float* __restrict__ w_hh, const float* __restrict__ P,
  float* __restrict__ h_buf, unsigned* __restrict__ cnt)
{
  extern __shared__ float sm[];
  float* Wt = sm;                 // [512][66] k-major: Wt[k*66 + r]
  float* ht = sm + 512*66;        // [512][13] k-major: ht[k*13 + b]
  int bid = blockIdx.x;
  int bg = bid & 15, js = bid >> 4;
  int tid = threadIdx.x;
  const float* Wgo = w_hh + (size_t)2*H_*H_;      // rows [0,512)=g, [512,1024)=o
  for (int it=0; it<32; ++it){                    // stage 64x512 weights
    int e4 = (it*256 + tid)*4;
    int k = e4 & 511, r = e4 >> 9;
    int jh_loc = 2*(r>>2) + (r&1);
    int part = (r>>1)&1;
    int grow = part*H_ + js*32 + jh_loc;
    float4 v = *(const float4*)(Wgo + (size_t)grow*H_ + k);
    Wt[(k+0)*66 + r] = v.x; Wt[(k+1)*66 + r] = v.y;
    Wt[(k+2)*66 + r] = v.z; Wt[(k+3)*66 + r] = v.w;
  }
  int rq = tid >> 4, kq = tid & 15;
  unsigned* mycnt = cnt + bg*64;                  // 256B-padded counter
  int gb = bg*8 + kq;                             // valid when kq<8
  int jcol = js*32 + 2*rq;
  float2 pg = {0.f,0.f}, po = {0.f,0.f};
  if (kq < 8){
    size_t prow = (size_t)gb*1024;                // t = 0
    pg = *(const float2*)&P[prow + jcol];
    po = *(const float2*)&P[prow + 512 + jcol];
  }
  __syncthreads();                                // weights staged before first compute
  for (int t=0; t<T_; ++t){
    int par = t & 1;
    const unsigned long long* hb =
      (const unsigned long long*)(h_buf + par*(B_*H_) + (bg*8)*H_);
    // stage h[8][512] -> k-major LDS via LLC-direct atomic loads (bypass L1/L2)
    #pragma unroll
    for (int b=0;b<8;++b){
      F2U64 v;
      v.u = __hip_atomic_load(&hb[b*(H_/2) + tid], __ATOMIC_RELAXED, __HIP_MEMORY_SCOPE_AGENT);
      ht[(2*tid)*13 + b]   = v.f.x;
      ht[(2*tid+1)*13 + b] = v.f.y;
    }
    __syncthreads();
    float acc[4][8] = {};
    #pragma unroll 4
    for (int kk=0; kk<32; ++kk){
      int k = kk*16 + kq;
      float2 wA = *(const float2*)&Wt[k*66 + 4*rq];
      float2 wB = *(const float2*)&Wt[k*66 + 4*rq + 2];
      float w0=wA.x, w1=wA.y, w2=wB.x, w3=wB.y;
      float hv[8];
      #pragma unroll
      for (int b=0;b<8;++b) hv[b] = ht[k*13 + b];
      #pragma unroll
      for (int b=0;b<8;++b){
        acc[0][b] = fmaf(w0, hv[b], acc[0][b]);
        acc[1][b] = fmaf(w1, hv[b], acc[1][b]);
        acc[2][b] = fmaf(w2, hv[b], acc[2][b]);
        acc[3][b] = fmaf(w3, hv[b], acc[3][b]);
      }
    }
    #pragma unroll
    for (int m=0;m<4;++m)
      #pragma unroll
      for (int b=0;b<8;++b){
        float v = acc[m][b];
        v += __shfl_xor(v, 1, 64);
        v += __shfl_xor(v, 2, 64);
        v += __shfl_xor(v, 4, 64);
        v += __shfl_xor(v, 8, 64);
        acc[m][b] = v;
      }
    if (kq < 8){
      int b = kq;
      float gg0 = acc[0][b] + pg.x, gg1 = acc[1][b] + pg.y;
      float oo0 = acc[2][b] + po.x, oo1 = acc[3][b] + po.y;
      F2U64 h2;
      h2.f.x = sigm_(oo0)*tanh_(tanh_(gg0));
      h2.f.y = sigm_(oo1)*tanh_(tanh_(gg1));
      __hip_atomic_store((unsigned long long*)&h_buf[(1-par)*(B_*H_) + gb*H_ + jcol],
                         h2.u, __ATOMIC_RELAXED, __HIP_MEMORY_SCOPE_AGENT);
    }
    __syncthreads();   // vmcnt(0): ht reusable AND h2 stores ACKed at LLC
    if (t+1 < T_){
      if (tid == 0)
        __hip_atomic_fetch_add(mycnt, 1u, __ATOMIC_RELAXED, __HIP_MEMORY_SCOPE_AGENT);
      // prefetch next step's P while we wait
      if (kq < 8){
        size_t prow = ((size_t)(t+1)*B_ + gb)*1024;
        pg = *(const float2*)&P[prow + jcol];
        po = *(const float2*)&P[prow + 512 + jcol];
      }
      unsigned target = (unsigned)(t+1)*16u;
      if (tid == 0){
        int guard = 0;
        while (__hip_atomic_load(mycnt, __ATOMIC_RELAXED, __HIP_MEMORY_SCOPE_AGENT) < target){
          __builtin_amdgcn_s_sleep(1);
          if (++guard > (1<<20)) break;            // safety bail
        }
      }
      __syncthreads();
    }
  }
}

// ---------------- classifier: out = hT @ w_out.T + b_out ----------------
__global__ __launch_bounds__(256) void k_cls(
  const float* __restrict__ hT, const float* __restrict__ w_out,
  const float* __restrict__ b_out, float* __restrict__ out)
{
  __shared__ float wt[32*68];     // [k][l] k-major
  __shared__ float htl[32*132];   // [k][b]
  int l0 = blockIdx.x * 64;       // 625 blocks
  int tid = threadIdx.x;
  int lq = tid >> 4, bq = tid & 15;
  float acc[4][8] = {};
  for (int kc=0; kc<16; ++kc){
    int k0 = kc*32;
    __syncthreads();
    for (int it=0; it<8; ++it){
      int e = it*256 + tid; int k = e & 31, l = e >> 5;
      wt[k*68 + l] = w_out[(size_t)(l0+l)*H_ + k0 + k];
    }
    for (int it=0; it<16; ++it){
      int e = it*256 + tid; int k = e & 31, b = e >> 5;
      htl[k*132 + b] = hT[b*H_ + k0 + k];
    }
    __syncthreads();
    #pragma unroll 4
    for (int k=0;k<32;++k){
      float4 w4 = *(const float4*)&wt[k*68 + lq*4];
      float4 h0 = *(const float4*)&htl[k*132 + bq*8];
      float4 h1 = *(const float4*)&htl[k*132 + bq*8 + 4];
      float wv[4] = {w4.x,w4.y,w4.z,w4.w};
      float hv[8] = {h0.x,h0.y,h0.z,h0.w,h1.x,h1.y,h1.z,h1.w};
      #pragma unroll
      for (int m=0;m<4;++m)
        #pragma unroll
        for (int i=0;i<8;++i) acc[m][i] = fmaf(wv[m], hv[i], acc[m][i]);
    }
  }
  int l = l0 + lq*4;
  float4 bo = *(const float4*)&b_out[l];
  #pragma unroll
  for (int i=0;i<8;++i){
    int b = bq*8 + i;
    float4 o4;
    o4.x = acc[0][i] + bo.x; o4.y = acc[1][i] + bo.y;
    o4.z = acc[2][i] + bo.z; o4.w = acc[3][i] + bo.w;
    *(float4*)&out[(size_t)b*L_ + l] = o4;
  }
}

extern "C" void kernel_launch(void* const* d_in, const int* in_sizes, int n_in,
                              void* d_out, int out_size, void* d_ws, size_t ws_size,
                              hipStream_t stream) {
  const int*   batch_l = (const int*)  d_in[0];
  const float* t_ld    = (const float*)d_in[1];
  const float* t_hd    = (const float*)d_in[2];
  const int*   t_l     = (const int*)  d_in[3];
  const int*   t_h     = (const int*)  d_in[4];
  const float* d_ld    = (const float*)d_in[5];
  const float* d_hd    = (const float*)d_in[6];
  const int*   d_l     = (const int*)  d_in[7];
  const int*   d_h     = (const int*)  d_in[8];
  const float* embed_l = (const float*)d_in[9];
  const float* embed_s = (const float*)d_in[10];
  const float* embed_q = (const float*)d_in[11];
  const float* w_ih    = (const float*)d_in[12];
  const float* w_hh    = (const float*)d_in[13];
  const float* w_s     = (const float*)d_in[14];
  const float* w_q     = (const float*)d_in[15];
  const float* b_ih    = (const float*)d_in[16];
  const float* b_hh    = (const float*)d_in[17];
  const float* w_out   = (const float*)d_in[18];
  const float* b_out   = (const float*)d_in[19];
  float* out = (float*)d_out;

  // workspace layout (floats)
  float* ws = (float*)d_ws;
  const size_t P_off  = 0;                          // 100*128*1024 = 13107200
  const size_t h_off  = 13107200;                   // 2*128*512 = 131072
  const size_t es_off = h_off + 131072;             // 5120
  const size_t eq_off = es_off + 5120;              // 5120
  const size_t cnt_off = eq_off + 5120;             // 1024 u32 (16 counters, 256B apart)
  const size_t need_bytes = (cnt_off + 1024)*4 + 64;
  if (ws_size < need_bytes) return;

  float* P       = ws + P_off;
  float* h_buf   = ws + h_off;
  float* es_proj = ws + es_off;
  float* eq_proj = ws + eq_off;
  unsigned* cnt  = (unsigned*)(ws + cnt_off);

  hipFuncSetAttribute(reinterpret_cast<const void*>(k_rec),
                      hipFuncAttributeMaxDynamicSharedMemorySize, 161792);

  k_zero<<<516, 256, 0, stream>>>(h_buf, cnt);
  k_prep<<<40, 256, 0, stream>>>(embed_s, embed_q, w_s, w_q, es_proj, eq_proj);
  k_phase1<<<dim3(200,16), 256, 0, stream>>>(batch_l, embed_l, w_ih, b_ih, b_hh,
      t_ld, t_hd, t_l, t_h, d_ld, d_hd, d_l, d_h, es_proj, eq_proj, P);
  k_rec<<<256, 256, 161792, stream>>>(w_hh, P, h_buf, cnt);
  k_cls<<<625, 256, 0, stream>>>(h_buf, w_out, b_out, out);
}